// Round 6
// baseline (12500.719 us; speedup 1.0000x reference)
//
#include <hip/hip_runtime.h>
#include <hip/hip_bf16.h>

// LSTM encoder: B=64, L=2048, D=256, 4D=1024, VOCAB=6000
// R6: zero-comm scan, occupancy-pinned register economics.
//   scan: 4 WGs x 512 thr (8 waves). amdgpu_waves_per_eu(2,2) -> 256 VGPR cap.
//   Per wave 64 U-frags: 40 in VGPRs, 16 in LDS (128KB), 8 streamed from L2
//   per step (~64KB/step/CU, hidden under MFMA). Anti-LICM iz guard keeps
//   loop-invariant loads inside the loop (R5 lesson: compiler remat/hoist).
//   h exchange via XOR-swizzled LDS double buffer, ONE raw s_barrier/step.
//   Tokens -> u8 mask array (1 load/lane/step), written over dead Wt region.

#define B_     64
#define L_     2048
#define D_     256
#define G4_    1024
#define VOCAB_ 6000

typedef short    s16x8 __attribute__((ext_vector_type(8)));
typedef float    f32x4 __attribute__((ext_vector_type(4)));
typedef unsigned u32x2 __attribute__((ext_vector_type(2)));
typedef unsigned u32x4 __attribute__((ext_vector_type(4)));

// ---- ws layout (bytes) ----
#define OFF_EMBB   0u            // VOCAB*D bf16 = 3,072,000
#define OFF_WT     3072000u      // W^T [n][k] bf16; REUSED as mask8 after xg
#define OFF_UF     3596288u      // U frag layout = 524,288
#define OFF_XG     4120576u      // [t][g][w][l][64B] = 268,435,456
#define WS_NEED    272556032u

#define SMEM_U     131072        // 8 waves x 16 frags x 1KB
#define SMEM_H     16384         // 2 bufs x 16 rows x 512B (swizzled)
#define SMEM_TOTAL (SMEM_U + SMEM_H)   // 147,456

__global__ void prep_kernel(const float* __restrict__ emb,
                            const float* __restrict__ W,
                            const float* __restrict__ U,
                            __hip_bfloat16* __restrict__ embb,
                            __hip_bfloat16* __restrict__ Wt,
                            __hip_bfloat16* __restrict__ Ufrag) {
  const int stride = gridDim.x * blockDim.x;
  const int i0 = blockIdx.x * blockDim.x + threadIdx.x;
  for (int i = i0; i < VOCAB_ * D_; i += stride)
    embb[i] = __float2bfloat16(emb[i]);
  for (int i = i0; i < D_ * G4_; i += stride) {
    int k = i >> 10;
    int n = i & (G4_ - 1);
    Wt[n * D_ + k] = __float2bfloat16(W[i]);
  }
  // U frag layout: elem i = ((w*64 + fj)*64 + l)*8 + j
  //   fj = kk*8 + s;  s = q*2 + nt
  //   n = q*256 + w*32 + nt*16 + (l&15);  k = kk*32 + (l>>4)*8 + j
  for (int i = i0; i < 8 * 64 * 64 * 8; i += stride) {
    int j  = i & 7;
    int l  = (i >> 3) & 63;
    int fj = (i >> 9) & 63;
    int w  = (i >> 15) & 7;
    int kk = fj >> 3, s = fj & 7;
    int q = s >> 1, nt = s & 1;
    int n = q * 256 + w * 32 + nt * 16 + (l & 15);
    int k = kk * 32 + (l >> 4) * 8 + j;
    Ufrag[i] = __float2bfloat16(U[k * G4_ + n]);
  }
}

// mask8[t*64+b] = (ctx[b][t] != 0) — runs AFTER xg_kernel, overwrites Wt
__global__ void mask_kernel(const int* __restrict__ ctx,
                            unsigned char* __restrict__ m8) {
  const int stride = gridDim.x * blockDim.x;
  for (int i = blockIdx.x * blockDim.x + threadIdx.x; i < B_ * L_; i += stride) {
    int b = i & 63, t = i >> 6;
    m8[t * 64 + b] = (ctx[b * L_ + t] != 0) ? 1 : 0;
  }
}

__device__ inline unsigned pk2(float a, float b) {
  return (unsigned)__bfloat16_as_ushort(__float2bfloat16(a)) |
         ((unsigned)__bfloat16_as_ushort(__float2bfloat16(b)) << 16);
}
__device__ inline float bl(unsigned u) {
  union { unsigned u; float f; } c; c.u = u << 16; return c.f;
}
__device__ inline float bh(unsigned u) {
  union { unsigned u; float f; } c; c.u = u & 0xffff0000u; return c.f;
}
__device__ inline float fsigmoid(float x) { return 1.f / (1.f + __expf(-x)); }
__device__ inline float ftanh(float x)    { return 1.f - 2.f / (__expf(2.f * x) + 1.f); }

// ---- xg precompute: grid 512 = 32 t-chunks x 4 groups x 4 gates ----
__global__ __launch_bounds__(256, 2)
void xg_kernel(const int* __restrict__ ctx,
               const __hip_bfloat16* __restrict__ embb,
               const __hip_bfloat16* __restrict__ Wt,
               char* __restrict__ xg) {
  const int bid = blockIdx.x;
  const int Q   = bid & 3;
  const int g   = (bid >> 2) & 3;
  const int tc  = bid >> 4;
  const int tid = threadIdx.x;
  const int wv  = tid >> 6;
  const int l   = tid & 63;
  const int l15 = l & 15, lhi = l >> 4;
  const int row0 = g * 16;

  s16x8 bfr[8][4];
#pragma unroll
  for (int nt = 0; nt < 4; ++nt) {
    const int n = Q * 256 + wv * 64 + nt * 16 + l15;
    const __hip_bfloat16* wp = Wt + n * D_ + lhi * 8;
#pragma unroll
    for (int kk = 0; kk < 8; ++kk)
      bfr[kk][nt] = *(const s16x8*)(wp + kk * 32);
  }

  for (int tt = 0; tt < 64; ++tt) {
    const int t = tc * 64 + tt;
    const int tok = ctx[(row0 + l15) * L_ + t];
    const __hip_bfloat16* xp = embb + tok * D_ + lhi * 8;
    s16x8 af[8];
#pragma unroll
    for (int kk = 0; kk < 8; ++kk)
      af[kk] = *(const s16x8*)(xp + kk * 32);

    f32x4 acc[4];
#pragma unroll
    for (int nt = 0; nt < 4; ++nt) acc[nt] = (f32x4){0.f, 0.f, 0.f, 0.f};
#pragma unroll
    for (int kk = 0; kk < 8; ++kk)
#pragma unroll
      for (int nt = 0; nt < 4; ++nt)
        acc[nt] = __builtin_amdgcn_mfma_f32_16x16x32_bf16(af[kk], bfr[kk][nt], acc[nt], 0, 0, 0);

#pragma unroll
    for (int nt = 0; nt < 4; ++nt) {
      const int ws = wv * 2 + (nt >> 1);
      const int s  = Q * 2 + (nt & 1);
      u32x2 vv;
      vv.x = pk2(acc[nt][0], acc[nt][1]);
      vv.y = pk2(acc[nt][2], acc[nt][3]);
      char* p = xg + (size_t)(((t * 4 + g) * 8 + ws) * 64 + l) * 64 + s * 8;
      *(u32x2*)p = vv;
    }
  }
}

// ---- scan: 4 WGs x 512 threads (8 waves, PINNED 2 waves/EU -> 256 VGPR) ----
__global__ __attribute__((amdgpu_flat_work_group_size(512, 512),
                          amdgpu_waves_per_eu(2, 2)))
void scan_kernel(const float* __restrict__ bias,
                 const __hip_bfloat16* __restrict__ Ufrag,
                 const char* __restrict__ xg,
                 const unsigned char* __restrict__ mask8,
                 float* __restrict__ out) {
  extern __shared__ __align__(16) char smem[];
  const int g   = blockIdx.x;
  const int tid = threadIdx.x;
  const int w   = tid >> 6;            // wave: d in [w*32, w*32+32)
  const int l   = tid & 63;
  const int l15 = l & 15, lhi = l >> 4;
  const int row0 = g * 16;

  const s16x8* uf = (const s16x8*)Ufrag;

  // U register tier: fj 0..39 (kk 0..4) = 160 VGPRs, persistent
  s16x8 ur[40];
#pragma unroll
  for (int fj = 0; fj < 40; ++fj)
    ur[fj] = uf[(w * 64 + fj) * 64 + l];

  // U LDS tier: fj 40..55 (kk 5..6) -> slot w*16 + i
  s16x8* ulds = (s16x8*)smem;
#pragma unroll
  for (int i = 0; i < 16; ++i)
    ulds[(w * 16 + i) * 64 + l] = uf[(w * 64 + 40 + i) * 64 + l];

  // zero h double-buffer
  {
    unsigned* hz = (unsigned*)(smem + SMEM_U);
    for (int i = tid; i < SMEM_H / 4; i += 512) hz[i] = 0;
  }

  // bias per strip s=q*2+nt: d = w*32 + (s&1)*16 + l15
  float bq[8];
#pragma unroll
  for (int s = 0; s < 8; ++s)
    bq[s] = bias[(s >> 1) * D_ + w * 32 + (s & 1) * 16 + l15];

  float c[8]  = {0.f, 0.f, 0.f, 0.f, 0.f, 0.f, 0.f, 0.f};
  float hp[8] = {0.f, 0.f, 0.f, 0.f, 0.f, 0.f, 0.f, 0.f};

  __syncthreads();

  const char* xgl = xg + ((size_t)(g * 8 + w) * 64 + l) * 64;
  const int swzr = (l15 & 7) << 4;

  for (int t = 0; t < L_; ++t) {
    // asm-opaque zero: blocks LICM/remat of "loop-invariant" tier loads
    int iz;
    asm volatile("v_mov_b32 %0, 0" : "=v"(iz));

    // ---- h(t-1) frags from swizzled LDS buf[t&1] (issued right after barrier)
    const char* hb = smem + SMEM_U + (t & 1) * 8192 + l15 * 512;
    s16x8 hf[8];
#pragma unroll
    for (int kk = 0; kk < 8; ++kk)
      hf[kk] = *(const s16x8*)(hb + ((kk * 64 + lhi * 16) ^ swzr));

    // ---- stream tier kk7 from L2 (8 frags; consumed at end of MFMA phase)
    s16x8 sb[8];
#pragma unroll
    for (int s = 0; s < 8; ++s)
      sb[s] = uf[(w * 64 + 56 + s) * 64 + l + iz];

    // ---- xg + mask for this step (consumed at elementwise)
    const u32x4* xp = (const u32x4*)(xgl + (size_t)t * 131072);
    union { u32x4 v[4]; unsigned u[16]; } xw;
    xw.v[0] = xp[0]; xw.v[1] = xp[1]; xw.v[2] = xp[2]; xw.v[3] = xp[3];
    const unsigned msk = *(const unsigned*)(mask8 + t * 64 + row0 + lhi * 4 + iz);

    // ---- MFMA: 64 per wave (8 k-bands x 8 strips)
    f32x4 acc[8];
#pragma unroll
    for (int s = 0; s < 8; ++s) acc[s] = (f32x4){0.f, 0.f, 0.f, 0.f};

#pragma unroll
    for (int kk = 0; kk < 5; ++kk)
#pragma unroll
      for (int s = 0; s < 8; ++s)
        acc[s] = __builtin_amdgcn_mfma_f32_16x16x32_bf16(hf[kk], ur[kk * 8 + s], acc[s], 0, 0, 0);

#pragma unroll
    for (int kk = 5; kk < 7; ++kk) {
      s16x8 ub[8];
#pragma unroll
      for (int s = 0; s < 8; ++s)
        ub[s] = ulds[(w * 16 + (kk - 5) * 8 + s) * 64 + l + iz];
#pragma unroll
      for (int s = 0; s < 8; ++s)
        acc[s] = __builtin_amdgcn_mfma_f32_16x16x32_bf16(hf[kk], ub[s], acc[s], 0, 0, 0);
    }

#pragma unroll
    for (int s = 0; s < 8; ++s)
      acc[s] = __builtin_amdgcn_mfma_f32_16x16x32_bf16(hf[7], sb[s], acc[s], 0, 0, 0);

    // ---- elementwise LSTM (8 cells/lane), h write to swizzled buf[(t+1)&1]
    char* hw = smem + SMEM_U + ((t + 1) & 1) * 8192;
#pragma unroll
    for (int nt = 0; nt < 2; ++nt)
#pragma unroll
      for (int r = 0; r < 4; ++r) {
        const int e  = nt * 4 + r;
        const int wi = nt * 2 + (r >> 1);
        const bool hi = (r & 1);
        float x0 = hi ? bh(xw.u[0 + wi])  : bl(xw.u[0 + wi]);
        float x1 = hi ? bh(xw.u[4 + wi])  : bl(xw.u[4 + wi]);
        float x2 = hi ? bh(xw.u[8 + wi])  : bl(xw.u[8 + wi]);
        float x3 = hi ? bh(xw.u[12 + wi]) : bl(xw.u[12 + wi]);
        float gi = acc[0 + nt][r] + x0 + bq[0 + nt];
        float gf = acc[2 + nt][r] + x1 + bq[2 + nt];
        float gc = acc[4 + nt][r] + x2 + bq[4 + nt];
        float go = acc[6 + nt][r] + x3 + bq[6 + nt];
        float i_ = fsigmoid(gi);
        float f_ = fsigmoid(gf);
        float o_ = fsigmoid(go);
        float cn = f_ * c[e] + i_ * ftanh(gc);
        float hn = o_ * ftanh(cn);
        const bool upd = ((msk >> (8 * r)) & 255u) != 0u;
        c[e]  = upd ? cn : c[e];
        hp[e] = upd ? hn : hp[e];
        const int row = lhi * 4 + r;
        const int d   = w * 32 + nt * 16 + l15;
        out[((size_t)(row0 + row) * L_ + t) * D_ + d] = hp[e];
        *(unsigned short*)(hw + row * 512 + ((2 * d) ^ ((row & 7) << 4))) =
            __bfloat16_as_ushort(__float2bfloat16(hp[e]));
      }

    asm volatile("s_waitcnt lgkmcnt(0)" ::: "memory");
    __builtin_amdgcn_s_barrier();
    __builtin_amdgcn_sched_barrier(0);
  }
}

extern "C" void kernel_launch(void* const* d_in, const int* in_sizes, int n_in,
                              void* d_out, int out_size, void* d_ws, size_t ws_size,
                              hipStream_t stream) {
  const int*   ctx  = (const int*)d_in[0];
  const float* emb  = (const float*)d_in[1];
  const float* W    = (const float*)d_in[2];
  const float* U    = (const float*)d_in[3];
  const float* bias = (const float*)d_in[4];
  float* out = (float*)d_out;

  char* ws = (char*)d_ws;
  __hip_bfloat16* embb = (__hip_bfloat16*)(ws + OFF_EMBB);
  __hip_bfloat16* Wt   = (__hip_bfloat16*)(ws + OFF_WT);
  __hip_bfloat16* Uf   = (__hip_bfloat16*)(ws + OFF_UF);
  unsigned char*  m8   = (unsigned char*)(ws + OFF_WT);   // reuse Wt after xg
  char*           xgb  = ws + OFF_XG;

  hipFuncSetAttribute((const void*)scan_kernel,
                      hipFuncAttributeMaxDynamicSharedMemorySize, SMEM_TOTAL);

  prep_kernel<<<1024, 256, 0, stream>>>(emb, W, U, embb, Wt, Uf);
  xg_kernel<<<512, 256, 0, stream>>>(ctx, embb, Wt, xgb);
  mask_kernel<<<128, 256, 0, stream>>>(ctx, m8);           // overwrites Wt (dead)
  scan_kernel<<<4, 512, SMEM_TOTAL, stream>>>(bias, Uf, xgb, m8, out);
}